// Round 6
// baseline (239.723 us; speedup 1.0000x reference)
//
#include <hip/hip_runtime.h>
#include <hip/hip_bf16.h>
#include <math.h>

typedef __attribute__((ext_vector_type(8)))  short short8;   // 8 bf16 (4 VGPRs) MFMA operand
typedef __attribute__((ext_vector_type(16))) float f32x16;   // 32x32 MFMA accumulator

constexpr int TB = 32;          // batch rows per block
constexpr int PLANE = 16384;    // one LDS split-plane: 32 rows * 256 k * 2B, row stride 512B
// XOR swizzle (row&7)<<4 spreads the stride-512B column accesses across 8 16B slots.

__device__ __forceinline__ float vexp2f(float x) {   // 2^x
    float r; asm("v_exp_f32 %0, %1" : "=v"(r) : "v"(x)); return r;
}

// packed RNE f32->bf16 pair: [31:16]=bf16(b), [15:0]=bf16(a)
__device__ __forceinline__ unsigned int cvtpk_bf16(float a, float b) {
    unsigned int r;
    asm("v_cvt_pk_bf16_f32 %0, %1, %2" : "=v"(r) : "v"(a), "v"(b));
    return r;
}

// 3-term split of two values at once; packed u32 outputs feed b16 stores directly.
// Exact: x = h + m + l + O(2^-24|x|).
__device__ __forceinline__ void split3_pair(float v0, float v1,
                                            unsigned int& hp, unsigned int& mp, unsigned int& lp) {
    hp = cvtpk_bf16(v0, v1);
    const float h0 = __uint_as_float(hp << 16);
    const float h1 = __uint_as_float(hp & 0xffff0000u);
    const float r0 = v0 - h0, r1 = v1 - h1;
    mp = cvtpk_bf16(r0, r1);
    const float m0 = __uint_as_float(mp << 16);
    const float m1 = __uint_as_float(mp & 0xffff0000u);
    lp = cvtpk_bf16(r0 - m0, r1 - m1);
}

// scalar split (pack_w only; perf-irrelevant)
__device__ __forceinline__ unsigned int bf16_rne_bits(float x) {
    unsigned int u = __float_as_uint(x);
    return (u + 0x7fffu + ((u >> 16) & 1u)) & 0xffff0000u;
}
__device__ __forceinline__ void split3(float x, unsigned short& h, unsigned short& m, unsigned short& l) {
    const unsigned int hb = bf16_rne_bits(x);
    const float r1 = x - __uint_as_float(hb);
    const unsigned int mb = bf16_rne_bits(r1);
    const float r2 = r1 - __uint_as_float(mb);
    h = (unsigned short)(hb >> 16);
    m = (unsigned short)(mb >> 16);
    l = (unsigned short)(__float_as_uint(r2) >> 16);
}

// Branchless per-node activation: 3 transcendentals total (v_sin, v_exp, v_rcp).
__device__ __forceinline__ float apply_act(int a, float x) {
    const float x2 = x * x;
    const float roff = (a == 10) ? 0.25f : 0.0f;
    const float r  = __builtin_amdgcn_fractf(fmaf(0.5f, x, roff));
    const float sn = __builtin_amdgcn_sinf(r);
    const float eop = (a == 4) ? x2 : x;
    const float ecf = (a == 4) ? -0.72134752044448169f
                               : ((a == 5) ? 2.8853900817779268f : -1.4426950408889634f);
    const float e  = vexp2f(eop * ecf);
    const float d  = __builtin_amdgcn_rcpf(1.0f + e);
    float ev = d;                                   // id 6: sigmoid
    ev = (a == 4) ? e : ev;                         // id 4: gauss
    ev = (a == 5) ? fmaf(-2.0f, d, 1.0f) : ev;      // id 5: tanh
    float v = x;
    v = (a == 2)  ? (x > 0.0f ? 1.0f : 0.0f) : v;
    v = (a == 3 || a == 10) ? sn : v;
    v = (a >= 4 && a <= 6)  ? ev : v;
    v = (a == 7)  ? -x : v;
    v = (a == 8)  ? fabsf(x) : v;
    v = (a == 9)  ? fmaxf(0.0f, x) : v;
    v = (a == 11) ? x2 : v;
    return v;
}

// ---------------- weight pre-pack (layout unchanged since round 2) ----------------
// ws: fragment-linear bf16. Group g = (layer, ktile t, ctile c):
//   L0: g = t*8+c (128) | L1: 128 + t*8+c | L2: 256 + t*4+c (64)
// ws[((g*3+s)*64 + lane)*8 + i] = split_s( W[k=t*16+(lane>>5)*8+i][col=c*32+(lane&31)] )
__global__ void pack_w(const float* __restrict__ W0, const float* __restrict__ W1,
                       const float* __restrict__ W2, unsigned short* __restrict__ ws) {
    const int g = blockIdx.x * 4 + (threadIdx.x >> 6);   // 0..319
    const int lane = threadIdx.x & 63;
    const int hi = lane >> 5, ln31 = lane & 31;
    const float* W; int t, c, ldw, rowoff;
    if (g < 128)      { W = W0; t = g >> 3;        c = g & 7;        ldw = 256; rowoff = 1; }
    else if (g < 256) { W = W1; t = (g-128) >> 3;  c = (g-128) & 7;  ldw = 256; rowoff = 0; }
    else              { W = W2; t = (g-256) >> 2;  c = (g-256) & 3;  ldw = 128; rowoff = 0; }
    const int col = c * 32 + ln31;
    unsigned short hb[8], mb[8], lb[8];
    #pragma unroll
    for (int i = 0; i < 8; ++i) {
        const int k = t * 16 + hi * 8 + i;
        split3(W[(size_t)(rowoff + k) * ldw + col], hb[i], mb[i], lb[i]);
    }
    size_t base = ((size_t)(g * 3 + 0) * 64 + lane) * 8;
    #pragma unroll
    for (int i = 0; i < 8; ++i) ws[base + i] = hb[i];
    base += 64 * 8;
    #pragma unroll
    for (int i = 0; i < 8; ++i) ws[base + i] = mb[i];
    base += 64 * 8;
    #pragma unroll
    for (int i = 0; i < 8; ++i) ws[base + i] = lb[i];
}

// ---------------- fused main kernel ----------------
// mfma_f32_32x32x16_bf16: A[row=lane&31][k=(lane>>5)*8+i], B[k][col=lane&31],
// D: col=lane&31, row=(reg&3)+8*(reg>>2)+4*(lane>>5)  (HW-verified rounds 2-5).
template<int NC_TOT>
__device__ __forceinline__ void gemm_layer(const short8* __restrict__ wsL, const char* smem,
                                           f32x16& acc, int ctile, int lane) {
    const int hi = lane >> 5, ln31 = lane & 31;
    const int abase = ln31 * 512;
    const int swzm = (ln31 & 7) << 4;
    const short8* bp = wsL + (size_t)ctile * 192 + lane;
    #pragma unroll 2
    for (int t = 0; t < 16; ++t) {
        const int koff = abase + ((t * 32 + hi * 16) ^ swzm);
        short8 ah = *(const short8*)(smem + 0 * PLANE + koff);
        short8 am = *(const short8*)(smem + 1 * PLANE + koff);
        short8 al = *(const short8*)(smem + 2 * PLANE + koff);
        short8 bh = bp[0];
        short8 bm = bp[64];
        short8 bl = bp[128];
        bp += NC_TOT * 192;
        __builtin_amdgcn_s_setprio(1);
        acc = __builtin_amdgcn_mfma_f32_32x32x16_bf16(ah, bh, acc, 0, 0, 0);
        acc = __builtin_amdgcn_mfma_f32_32x32x16_bf16(ah, bm, acc, 0, 0, 0);
        acc = __builtin_amdgcn_mfma_f32_32x32x16_bf16(am, bh, acc, 0, 0, 0);
        acc = __builtin_amdgcn_mfma_f32_32x32x16_bf16(ah, bl, acc, 0, 0, 0);
        acc = __builtin_amdgcn_mfma_f32_32x32x16_bf16(am, bm, acc, 0, 0, 0);
        acc = __builtin_amdgcn_mfma_f32_32x32x16_bf16(al, bh, acc, 0, 0, 0);
        __builtin_amdgcn_s_setprio(0);
    }
}

// activation (in-place, pre-barrier, register-only) + pair-split + store to LDS planes
__device__ __forceinline__ void act_store_lds(f32x16& acc, const int* __restrict__ act,
                                              char* smem, int ctile, int lane) {
    const int hi = lane >> 5, ln31 = lane & 31;
    const int col = ctile * 32 + ln31;
    const int aid = act[col];
    const int kbyte = 2 * col;
    #pragma unroll
    for (int rr = 0; rr < 16; ++rr) acc[rr] = apply_act(aid, acc[rr]);  // overlaps other waves' reads
    __syncthreads();   // everyone done reading previous planes
    #pragma unroll
    for (int p = 0; p < 8; ++p) {
        const int rr0 = 2 * p;
        unsigned int hp, mp, lp;
        split3_pair(acc[rr0], acc[rr0 + 1], hp, mp, lp);
        const int row0 = (rr0 & 3) + 8 * (rr0 >> 2) + 4 * hi;   // rr0 even -> rr0+1 = row0+1
        const int a0 = row0 * 512 + (kbyte ^ ((row0 & 7) << 4));
        const int a1 = (row0 + 1) * 512 + (kbyte ^ (((row0 + 1) & 7) << 4));
        *(unsigned short*)(smem + 0 * PLANE + a0) = (unsigned short)hp;
        *(unsigned short*)(smem + 0 * PLANE + a1) = (unsigned short)(hp >> 16);
        *(unsigned short*)(smem + 1 * PLANE + a0) = (unsigned short)mp;
        *(unsigned short*)(smem + 1 * PLANE + a1) = (unsigned short)(mp >> 16);
        *(unsigned short*)(smem + 2 * PLANE + a0) = (unsigned short)lp;
        *(unsigned short*)(smem + 2 * PLANE + a1) = (unsigned short)(lp >> 16);
    }
    __syncthreads();
}

__global__ __launch_bounds__(512, 6)
void wann_mfma(const float* __restrict__ x,
               const float* __restrict__ W0,
               const unsigned short* __restrict__ ws,
               const int* __restrict__ a1, const int* __restrict__ a2,
               const int* __restrict__ a3,
               float* __restrict__ out) {
    extern __shared__ char smem[];           // 3 planes x 16 KiB
    const int tid = threadIdx.x;
    const int lane = tid & 63;
    const int wid = tid >> 6;                // 0..7 = ctile
    const int ln31 = lane & 31;
    const int hi = lane >> 5;
    const int row0 = blockIdx.x * TB;

    // ---- stage x[row0:row0+32, :]: float4 -> pair-split -> b64 LDS writes ----
    {
        const float4* xv = (const float4*)(x + (size_t)row0 * 256);
        #pragma unroll
        for (int p = 0; p < 4; ++p) {
            const int f = p * 512 + tid;     // 0..2047
            const int r = f >> 6;            // row 0..31
            const int swz = (r & 7) << 4;
            const int kb0 = (f & 63) * 8;    // byte offset of the 4 bf16 slots (8B aligned)
            const float4 v = xv[f];
            unsigned int h01, m01, l01, h23, m23, l23;
            split3_pair(v.x, v.y, h01, m01, l01);
            split3_pair(v.z, v.w, h23, m23, l23);
            // swizzle only flips bits 4-6 -> 8B block stays contiguous & aligned
            const int a0 = r * 512 + (kb0 ^ swz);
            *(unsigned long long*)(smem + 0 * PLANE + a0) =
                (unsigned long long)h01 | ((unsigned long long)h23 << 32);
            *(unsigned long long*)(smem + 1 * PLANE + a0) =
                (unsigned long long)m01 | ((unsigned long long)m23 << 32);
            *(unsigned long long*)(smem + 2 * PLANE + a0) =
                (unsigned long long)l01 | ((unsigned long long)l23 << 32);
        }
    }
    __syncthreads();

    const short8* wsv  = (const short8*)ws;
    const short8* wsL0 = wsv;
    const short8* wsL1 = wsv + (size_t)128 * 3 * 64;
    const short8* wsL2 = wsv + (size_t)256 * 3 * 64;

    f32x16 acc;

    // ---- layer 1 (bias = W0 row 0), ctile = wid ----
    {
        const float b = W0[wid * 32 + ln31];
        #pragma unroll
        for (int rr = 0; rr < 16; ++rr) acc[rr] = b;
        gemm_layer<8>(wsL0, smem, acc, wid, lane);
        act_store_lds(acc, a1, smem, wid, lane);
    }

    // ---- layer 2 ----
    {
        #pragma unroll
        for (int rr = 0; rr < 16; ++rr) acc[rr] = 0.0f;
        gemm_layer<8>(wsL1, smem, acc, wid, lane);
        act_store_lds(acc, a2, smem, wid, lane);
    }

    // ---- layer 3: 128 cols -> waves 0..3, direct store ----
    if (wid < 4) {
        #pragma unroll
        for (int rr = 0; rr < 16; ++rr) acc[rr] = 0.0f;
        gemm_layer<4>(wsL2, smem, acc, wid, lane);
        const int col = wid * 32 + ln31;
        const int aid = a3[col];
        #pragma unroll
        for (int rr = 0; rr < 16; ++rr) {
            const float v = apply_act(aid, acc[rr]);
            const int orow = (rr & 3) + 8 * (rr >> 2) + 4 * hi;
            out[(size_t)(row0 + orow) * 128 + col] = v;
        }
    }
}

extern "C" void kernel_launch(void* const* d_in, const int* in_sizes, int n_in,
                              void* d_out, int out_size, void* d_ws, size_t ws_size,
                              hipStream_t stream) {
    const float* x  = (const float*)d_in[0];
    const float* W0 = (const float*)d_in[1];   // [257,256], row 0 = bias
    const float* W1 = (const float*)d_in[2];   // [256,256]
    const float* W2 = (const float*)d_in[3];   // [256,128]
    const int*   a1 = (const int*)d_in[4];
    const int*   a2 = (const int*)d_in[5];
    const int*   a3 = (const int*)d_in[6];
    float* out = (float*)d_out;

    unsigned short* ws = (unsigned short*)d_ws;   // 983040 B packed bf16 fragments

    hipFuncSetAttribute(reinterpret_cast<const void*>(wann_mfma),
                        hipFuncAttributeMaxDynamicSharedMemorySize, 3 * PLANE);

    hipLaunchKernelGGL(pack_w, dim3(80), dim3(256), 0, stream, W0, W1, W2, ws);

    const int B = in_sizes[0] / 256;           // 65536
    hipLaunchKernelGGL(wann_mfma, dim3(B / TB), dim3(512), 3 * PLANE, stream,
                       x, W0, ws, a1, a2, a3, out);
}

// Round 7
// 224.534 us; speedup vs baseline: 1.0676x; 1.0676x over previous
//
#include <hip/hip_runtime.h>
#include <hip/hip_bf16.h>
#include <math.h>

typedef __attribute__((ext_vector_type(8)))  short short8;   // 8 bf16 (4 VGPRs) MFMA operand
typedef __attribute__((ext_vector_type(16))) float f32x16;   // 32x32 MFMA accumulator

constexpr int TB = 32;          // batch rows per block
constexpr int PLANE = 16384;    // one LDS split-plane: 32 rows * 256 k * 2B, row stride 512B
// XOR swizzle (row&7)<<4 spreads the stride-512B column accesses across 8 16B slots.

__device__ __forceinline__ float vexp2f(float x) {   // 2^x
    float r; asm("v_exp_f32 %0, %1" : "=v"(r) : "v"(x)); return r;
}

// packed RNE f32->bf16 pair: [31:16]=bf16(b), [15:0]=bf16(a)
__device__ __forceinline__ unsigned int cvtpk_bf16(float a, float b) {
    unsigned int r;
    asm("v_cvt_pk_bf16_f32 %0, %1, %2" : "=v"(r) : "v"(a), "v"(b));
    return r;
}

// 3-term split of two values at once; packed u32 outputs feed b16 stores directly.
// Exact: x = h + m + l + O(2^-24|x|).
__device__ __forceinline__ void split3_pair(float v0, float v1,
                                            unsigned int& hp, unsigned int& mp, unsigned int& lp) {
    hp = cvtpk_bf16(v0, v1);
    const float h0 = __uint_as_float(hp << 16);
    const float h1 = __uint_as_float(hp & 0xffff0000u);
    const float r0 = v0 - h0, r1 = v1 - h1;
    mp = cvtpk_bf16(r0, r1);
    const float m0 = __uint_as_float(mp << 16);
    const float m1 = __uint_as_float(mp & 0xffff0000u);
    lp = cvtpk_bf16(r0 - m0, r1 - m1);
}

// scalar split (pack_w only; perf-irrelevant)
__device__ __forceinline__ unsigned int bf16_rne_bits(float x) {
    unsigned int u = __float_as_uint(x);
    return (u + 0x7fffu + ((u >> 16) & 1u)) & 0xffff0000u;
}
__device__ __forceinline__ void split3(float x, unsigned short& h, unsigned short& m, unsigned short& l) {
    const unsigned int hb = bf16_rne_bits(x);
    const float r1 = x - __uint_as_float(hb);
    const unsigned int mb = bf16_rne_bits(r1);
    const float r2 = r1 - __uint_as_float(mb);
    h = (unsigned short)(hb >> 16);
    m = (unsigned short)(mb >> 16);
    l = (unsigned short)(__float_as_uint(r2) >> 16);
}

// Branchless per-node activation: 3 transcendentals total (v_sin, v_exp, v_rcp).
__device__ __forceinline__ float apply_act(int a, float x) {
    const float x2 = x * x;
    const float roff = (a == 10) ? 0.25f : 0.0f;
    const float r  = __builtin_amdgcn_fractf(fmaf(0.5f, x, roff));
    const float sn = __builtin_amdgcn_sinf(r);
    const float eop = (a == 4) ? x2 : x;
    const float ecf = (a == 4) ? -0.72134752044448169f
                               : ((a == 5) ? 2.8853900817779268f : -1.4426950408889634f);
    const float e  = vexp2f(eop * ecf);
    const float d  = __builtin_amdgcn_rcpf(1.0f + e);
    float ev = d;                                   // id 6: sigmoid
    ev = (a == 4) ? e : ev;                         // id 4: gauss
    ev = (a == 5) ? fmaf(-2.0f, d, 1.0f) : ev;      // id 5: tanh
    float v = x;
    v = (a == 2)  ? (x > 0.0f ? 1.0f : 0.0f) : v;
    v = (a == 3 || a == 10) ? sn : v;
    v = (a >= 4 && a <= 6)  ? ev : v;
    v = (a == 7)  ? -x : v;
    v = (a == 8)  ? fabsf(x) : v;
    v = (a == 9)  ? fmaxf(0.0f, x) : v;
    v = (a == 11) ? x2 : v;
    return v;
}

// ---------------- weight pre-pack (layout unchanged since round 2) ----------------
// ws: fragment-linear bf16. Group g = (layer, ktile t, ctile c):
//   L0: g = t*8+c (128) | L1: 128 + t*8+c | L2: 256 + t*4+c (64)
// ws[((g*3+s)*64 + lane)*8 + i] = split_s( W[k=t*16+(lane>>5)*8+i][col=c*32+(lane&31)] )
__global__ void pack_w(const float* __restrict__ W0, const float* __restrict__ W1,
                       const float* __restrict__ W2, unsigned short* __restrict__ ws) {
    const int g = blockIdx.x * 4 + (threadIdx.x >> 6);   // 0..319
    const int lane = threadIdx.x & 63;
    const int hi = lane >> 5, ln31 = lane & 31;
    const float* W; int t, c, ldw, rowoff;
    if (g < 128)      { W = W0; t = g >> 3;        c = g & 7;        ldw = 256; rowoff = 1; }
    else if (g < 256) { W = W1; t = (g-128) >> 3;  c = (g-128) & 7;  ldw = 256; rowoff = 0; }
    else              { W = W2; t = (g-256) >> 2;  c = (g-256) & 3;  ldw = 128; rowoff = 0; }
    const int col = c * 32 + ln31;
    unsigned short hb[8], mb[8], lb[8];
    #pragma unroll
    for (int i = 0; i < 8; ++i) {
        const int k = t * 16 + hi * 8 + i;
        split3(W[(size_t)(rowoff + k) * ldw + col], hb[i], mb[i], lb[i]);
    }
    size_t base = ((size_t)(g * 3 + 0) * 64 + lane) * 8;
    #pragma unroll
    for (int i = 0; i < 8; ++i) ws[base + i] = hb[i];
    base += 64 * 8;
    #pragma unroll
    for (int i = 0; i < 8; ++i) ws[base + i] = mb[i];
    base += 64 * 8;
    #pragma unroll
    for (int i = 0; i < 8; ++i) ws[base + i] = lb[i];
}

// ---------------- fused main kernel ----------------
// mfma_f32_32x32x16_bf16: A[row=lane&31][k=(lane>>5)*8+i], B[k][col=lane&31],
// D: col=lane&31, row=(reg&3)+8*(reg>>2)+4*(lane>>5)  (HW-verified rounds 2-6).
// t=t0's B fragments arrive preloaded (issued before the preceding barrier).
template<int NC_TOT, int NKT>
__device__ __forceinline__ void gemm_layer(const short8* __restrict__ wsL, const char* smem,
                                           f32x16& acc, int ctile, int lane, int t0,
                                           short8 bh, short8 bm, short8 bl) {
    const int hi = lane >> 5, ln31 = lane & 31;
    const int abase = ln31 * 512;
    const int swzm = (ln31 & 7) << 4;
    // peeled t = t0 with preloaded B
    {
        const int koff = abase + ((t0 * 32 + hi * 16) ^ swzm);
        short8 ah = *(const short8*)(smem + 0 * PLANE + koff);
        short8 am = *(const short8*)(smem + 1 * PLANE + koff);
        short8 al = *(const short8*)(smem + 2 * PLANE + koff);
        acc = __builtin_amdgcn_mfma_f32_32x32x16_bf16(ah, bh, acc, 0, 0, 0);
        acc = __builtin_amdgcn_mfma_f32_32x32x16_bf16(ah, bm, acc, 0, 0, 0);
        acc = __builtin_amdgcn_mfma_f32_32x32x16_bf16(am, bh, acc, 0, 0, 0);
        acc = __builtin_amdgcn_mfma_f32_32x32x16_bf16(ah, bl, acc, 0, 0, 0);
        acc = __builtin_amdgcn_mfma_f32_32x32x16_bf16(am, bm, acc, 0, 0, 0);
        acc = __builtin_amdgcn_mfma_f32_32x32x16_bf16(al, bh, acc, 0, 0, 0);
    }
    const short8* bp = wsL + ((size_t)(t0 + 1) * NC_TOT + ctile) * 192 + lane;
    #pragma unroll 2
    for (int t = t0 + 1; t < t0 + NKT; ++t) {
        const int koff = abase + ((t * 32 + hi * 16) ^ swzm);
        short8 ah = *(const short8*)(smem + 0 * PLANE + koff);
        short8 am = *(const short8*)(smem + 1 * PLANE + koff);
        short8 al = *(const short8*)(smem + 2 * PLANE + koff);
        short8 cbh = bp[0];
        short8 cbm = bp[64];
        short8 cbl = bp[128];
        bp += NC_TOT * 192;
        acc = __builtin_amdgcn_mfma_f32_32x32x16_bf16(ah, cbh, acc, 0, 0, 0);
        acc = __builtin_amdgcn_mfma_f32_32x32x16_bf16(ah, cbm, acc, 0, 0, 0);
        acc = __builtin_amdgcn_mfma_f32_32x32x16_bf16(am, cbh, acc, 0, 0, 0);
        acc = __builtin_amdgcn_mfma_f32_32x32x16_bf16(ah, cbl, acc, 0, 0, 0);
        acc = __builtin_amdgcn_mfma_f32_32x32x16_bf16(am, cbm, acc, 0, 0, 0);
        acc = __builtin_amdgcn_mfma_f32_32x32x16_bf16(al, cbh, acc, 0, 0, 0);
    }
}

// activation (in-place, pre-barrier, register-only) + pair-split + store to LDS planes.
// NOTE: no trailing barrier — caller issues next-layer B prefetch, then __syncthreads().
__device__ __forceinline__ void act_store_lds(f32x16& acc, const int* __restrict__ act,
                                              char* smem, int ctile, int lane) {
    const int hi = lane >> 5, ln31 = lane & 31;
    const int col = ctile * 32 + ln31;
    const int aid = act[col];
    const int kbyte = 2 * col;
    #pragma unroll
    for (int rr = 0; rr < 16; ++rr) acc[rr] = apply_act(aid, acc[rr]);  // overlaps other waves' reads
    __syncthreads();   // everyone done reading previous planes
    #pragma unroll
    for (int p = 0; p < 8; ++p) {
        const int rr0 = 2 * p;
        unsigned int hp, mp, lp;
        split3_pair(acc[rr0], acc[rr0 + 1], hp, mp, lp);
        const int row0 = (rr0 & 3) + 8 * (rr0 >> 2) + 4 * hi;   // rr0 even -> rr0+1 = row0+1
        const int a0 = row0 * 512 + (kbyte ^ ((row0 & 7) << 4));
        const int a1 = (row0 + 1) * 512 + (kbyte ^ (((row0 + 1) & 7) << 4));
        *(unsigned short*)(smem + 0 * PLANE + a0) = (unsigned short)hp;
        *(unsigned short*)(smem + 0 * PLANE + a1) = (unsigned short)(hp >> 16);
        *(unsigned short*)(smem + 1 * PLANE + a0) = (unsigned short)mp;
        *(unsigned short*)(smem + 1 * PLANE + a1) = (unsigned short)(mp >> 16);
        *(unsigned short*)(smem + 2 * PLANE + a0) = (unsigned short)lp;
        *(unsigned short*)(smem + 2 * PLANE + a1) = (unsigned short)(lp >> 16);
    }
}

__global__ __launch_bounds__(512, 6)
void wann_mfma(const float* __restrict__ x,
               const float* __restrict__ W0,
               const unsigned short* __restrict__ ws,
               const int* __restrict__ a1, const int* __restrict__ a2,
               const int* __restrict__ a3,
               float* __restrict__ out) {
    extern __shared__ char smem[];           // 3 planes x 16 KiB
    const int tid = threadIdx.x;
    const int lane = tid & 63;
    const int wid = tid >> 6;                // 0..7 = ctile (L1/L2)
    const int ln31 = lane & 31;
    const int hi = lane >> 5;
    const int row0 = blockIdx.x * TB;

    const short8* wsv  = (const short8*)ws;
    const short8* wsL0 = wsv;
    const short8* wsL1 = wsv + (size_t)128 * 3 * 64;
    const short8* wsL2 = wsv + (size_t)256 * 3 * 64;

    // ---- issue layer-1 t=0 B prefetch before staging (drains under staging) ----
    const short8* p0 = wsL0 + (size_t)wid * 192 + lane;
    short8 b0h = p0[0], b0m = p0[64], b0l = p0[128];

    // ---- stage x[row0:row0+32, :]: float4 -> pair-split -> b64 LDS writes ----
    {
        const float4* xv = (const float4*)(x + (size_t)row0 * 256);
        #pragma unroll
        for (int p = 0; p < 4; ++p) {
            const int f = p * 512 + tid;     // 0..2047
            const int r = f >> 6;            // row 0..31
            const int swz = (r & 7) << 4;
            const int kb0 = (f & 63) * 8;    // byte offset of the 4 bf16 slots (8B aligned)
            const float4 v = xv[f];
            unsigned int h01, m01, l01, h23, m23, l23;
            split3_pair(v.x, v.y, h01, m01, l01);
            split3_pair(v.z, v.w, h23, m23, l23);
            // swizzle only flips bits 4-6 -> 8B block stays contiguous & aligned
            const int a0 = r * 512 + (kb0 ^ swz);
            *(unsigned long long*)(smem + 0 * PLANE + a0) =
                (unsigned long long)h01 | ((unsigned long long)h23 << 32);
            *(unsigned long long*)(smem + 1 * PLANE + a0) =
                (unsigned long long)m01 | ((unsigned long long)m23 << 32);
            *(unsigned long long*)(smem + 2 * PLANE + a0) =
                (unsigned long long)l01 | ((unsigned long long)l23 << 32);
        }
    }
    __syncthreads();

    f32x16 acc;

    // ---- layer 1 (bias = W0 row 0), ctile = wid ----
    {
        const float b = W0[wid * 32 + ln31];
        #pragma unroll
        for (int rr = 0; rr < 16; ++rr) acc[rr] = b;
        gemm_layer<8, 16>(wsL0, smem, acc, wid, lane, 0, b0h, b0m, b0l);
        act_store_lds(acc, a1, smem, wid, lane);
    }
    // layer-2 t=0 B prefetch across the barrier
    const short8* p1 = wsL1 + (size_t)wid * 192 + lane;
    short8 b1h = p1[0], b1m = p1[64], b1l = p1[128];
    __syncthreads();

    // ---- layer 2 ----
    {
        #pragma unroll
        for (int rr = 0; rr < 16; ++rr) acc[rr] = 0.0f;
        gemm_layer<8, 16>(wsL1, smem, acc, wid, lane, 0, b1h, b1m, b1l);
        act_store_lds(acc, a2, smem, wid, lane);
    }
    // ---- layer 3: split-K, all 8 waves. wave = (kh, c3) ----
    const int c3 = wid & 3, kh = wid >> 2, t0 = kh * 8;
    const short8* p2 = wsL2 + ((size_t)(t0 * 4 + c3)) * 192 + lane;
    short8 b2h = p2[0], b2m = p2[64], b2l = p2[128];
    __syncthreads();

    {
        #pragma unroll
        for (int rr = 0; rr < 16; ++rr) acc[rr] = 0.0f;
        gemm_layer<4, 8>(wsL2, smem, acc, c3, lane, t0, b2h, b2m, b2l);
    }
    __syncthreads();                          // all plane reads done; planes reusable
    float* red = (float*)smem;                // 16 KB scratch for k-half partials
    if (kh == 1) {
        const int base = ((wid - 4) * 64 + lane) * 16;
        #pragma unroll
        for (int q = 0; q < 4; ++q) {
            float4 v = make_float4(acc[4*q], acc[4*q+1], acc[4*q+2], acc[4*q+3]);
            *(float4*)(red + base + 4 * q) = v;
        }
    }
    __syncthreads();
    if (kh == 0) {
        const int base = (wid * 64 + lane) * 16;
        #pragma unroll
        for (int q = 0; q < 4; ++q) {
            const float4 v = *(const float4*)(red + base + 4 * q);
            acc[4*q] += v.x; acc[4*q+1] += v.y; acc[4*q+2] += v.z; acc[4*q+3] += v.w;
        }
        const int col = c3 * 32 + ln31;
        const int aid = a3[col];
        #pragma unroll
        for (int rr = 0; rr < 16; ++rr) {
            const float v = apply_act(aid, acc[rr]);
            const int orow = (rr & 3) + 8 * (rr >> 2) + 4 * hi;
            out[(size_t)(row0 + orow) * 128 + col] = v;
        }
    }
}

extern "C" void kernel_launch(void* const* d_in, const int* in_sizes, int n_in,
                              void* d_out, int out_size, void* d_ws, size_t ws_size,
                              hipStream_t stream) {
    const float* x  = (const float*)d_in[0];
    const float* W0 = (const float*)d_in[1];   // [257,256], row 0 = bias
    const float* W1 = (const float*)d_in[2];   // [256,256]
    const float* W2 = (const float*)d_in[3];   // [256,128]
    const int*   a1 = (const int*)d_in[4];
    const int*   a2 = (const int*)d_in[5];
    const int*   a3 = (const int*)d_in[6];
    float* out = (float*)d_out;

    unsigned short* ws = (unsigned short*)d_ws;   // 983040 B packed bf16 fragments

    hipFuncSetAttribute(reinterpret_cast<const void*>(wann_mfma),
                        hipFuncAttributeMaxDynamicSharedMemorySize, 3 * PLANE);

    hipLaunchKernelGGL(pack_w, dim3(80), dim3(256), 0, stream, W0, W1, W2, ws);

    const int B = in_sizes[0] / 256;           // 65536
    hipLaunchKernelGGL(wann_mfma, dim3(B / TB), dim3(512), 3 * PLANE, stream,
                       x, W0, ws, a1, a2, a3, out);
}

// Round 8
// 197.214 us; speedup vs baseline: 1.2155x; 1.1385x over previous
//
#include <hip/hip_runtime.h>
#include <hip/hip_bf16.h>
#include <math.h>

typedef __attribute__((ext_vector_type(8)))  short short8;   // 8 bf16 (4 VGPRs) MFMA operand
typedef __attribute__((ext_vector_type(16))) float f32x16;   // 32x32 MFMA accumulator

constexpr int TB = 32;          // batch rows per block
constexpr int PLANE = 16384;    // one LDS split-plane: 32 rows * 256 k * 2B, row stride 512B
// XOR swizzle (row&7)<<4 spreads the stride-512B column accesses across 8 16B slots.

__device__ __forceinline__ float vexp2f(float x) {   // 2^x
    float r; asm("v_exp_f32 %0, %1" : "=v"(r) : "v"(x)); return r;
}

// packed RNE f32->bf16 pair: [31:16]=bf16(b), [15:0]=bf16(a)
__device__ __forceinline__ unsigned int cvtpk_bf16(float a, float b) {
    unsigned int r;
    asm("v_cvt_pk_bf16_f32 %0, %1, %2" : "=v"(r) : "v"(a), "v"(b));
    return r;
}

// 2-term split of two values at once: x = h + m + O(2^-16|x|)
__device__ __forceinline__ void split2_pair(float v0, float v1,
                                            unsigned int& hp, unsigned int& mp) {
    hp = cvtpk_bf16(v0, v1);
    const float h0 = __uint_as_float(hp << 16);
    const float h1 = __uint_as_float(hp & 0xffff0000u);
    mp = cvtpk_bf16(v0 - h0, v1 - h1);
}

// scalar split (pack_w only; perf-irrelevant)
__device__ __forceinline__ unsigned int bf16_rne_bits(float x) {
    unsigned int u = __float_as_uint(x);
    return (u + 0x7fffu + ((u >> 16) & 1u)) & 0xffff0000u;
}
__device__ __forceinline__ void split2(float x, unsigned short& h, unsigned short& m) {
    const unsigned int hb = bf16_rne_bits(x);
    const float r1 = x - __uint_as_float(hb);
    const unsigned int mb = bf16_rne_bits(r1);
    h = (unsigned short)(hb >> 16);
    m = (unsigned short)(mb >> 16);
}

// Branchless per-node activation: 3 transcendentals total (v_sin, v_exp, v_rcp).
__device__ __forceinline__ float apply_act(int a, float x) {
    const float x2 = x * x;
    const float roff = (a == 10) ? 0.25f : 0.0f;
    const float r  = __builtin_amdgcn_fractf(fmaf(0.5f, x, roff));
    const float sn = __builtin_amdgcn_sinf(r);
    const float eop = (a == 4) ? x2 : x;
    const float ecf = (a == 4) ? -0.72134752044448169f
                               : ((a == 5) ? 2.8853900817779268f : -1.4426950408889634f);
    const float e  = vexp2f(eop * ecf);
    const float d  = __builtin_amdgcn_rcpf(1.0f + e);
    float ev = d;                                   // id 6: sigmoid
    ev = (a == 4) ? e : ev;                         // id 4: gauss
    ev = (a == 5) ? fmaf(-2.0f, d, 1.0f) : ev;      // id 5: tanh
    float v = x;
    v = (a == 2)  ? (x > 0.0f ? 1.0f : 0.0f) : v;
    v = (a == 3 || a == 10) ? sn : v;
    v = (a >= 4 && a <= 6)  ? ev : v;
    v = (a == 7)  ? -x : v;
    v = (a == 8)  ? fabsf(x) : v;
    v = (a == 9)  ? fmaxf(0.0f, x) : v;
    v = (a == 11) ? x2 : v;
    return v;
}

// ---------------- weight pre-pack (2 splits per fragment group) ----------------
// ws: fragment-linear bf16. Group g = (layer, ktile t, ctile c):
//   L0: g = t*8+c (128) | L1: 128 + t*8+c | L2: 256 + t*4+c (64)
// ws[((g*2+s)*64 + lane)*8 + i] = split_s( W[k=t*16+(lane>>5)*8+i][col=c*32+(lane&31)] )
__global__ void pack_w(const float* __restrict__ W0, const float* __restrict__ W1,
                       const float* __restrict__ W2, unsigned short* __restrict__ ws) {
    const int g = blockIdx.x * 4 + (threadIdx.x >> 6);   // 0..319
    const int lane = threadIdx.x & 63;
    const int hi = lane >> 5, ln31 = lane & 31;
    const float* W; int t, c, ldw, rowoff;
    if (g < 128)      { W = W0; t = g >> 3;        c = g & 7;        ldw = 256; rowoff = 1; }
    else if (g < 256) { W = W1; t = (g-128) >> 3;  c = (g-128) & 7;  ldw = 256; rowoff = 0; }
    else              { W = W2; t = (g-256) >> 2;  c = (g-256) & 3;  ldw = 128; rowoff = 0; }
    const int col = c * 32 + ln31;
    unsigned short hb[8], mb[8];
    #pragma unroll
    for (int i = 0; i < 8; ++i) {
        const int k = t * 16 + hi * 8 + i;
        split2(W[(size_t)(rowoff + k) * ldw + col], hb[i], mb[i]);
    }
    size_t base = ((size_t)(g * 2 + 0) * 64 + lane) * 8;
    #pragma unroll
    for (int i = 0; i < 8; ++i) ws[base + i] = hb[i];
    base += 64 * 8;
    #pragma unroll
    for (int i = 0; i < 8; ++i) ws[base + i] = mb[i];
}

// ---------------- fused main kernel ----------------
// mfma_f32_32x32x16_bf16: A[row=lane&31][k=(lane>>5)*8+i], B[k][col=lane&31],
// D: col=lane&31, row=(reg&3)+8*(reg>>2)+4*(lane>>5)  (HW-verified rounds 2-7).
// 3-MFMA split: hh + hm + mh  (drops mm ~2^-16 rel — absmax check is this round's probe).
// t=t0's B fragments arrive preloaded (issued before the preceding barrier).
template<int NC_TOT, int NKT>
__device__ __forceinline__ void gemm_layer(const short8* __restrict__ wsL, const char* smem,
                                           f32x16& acc, int ctile, int lane, int t0,
                                           short8 bh, short8 bm) {
    const int hi = lane >> 5, ln31 = lane & 31;
    const int abase = ln31 * 512;
    const int swzm = (ln31 & 7) << 4;
    // peeled t = t0 with preloaded B
    {
        const int koff = abase + ((t0 * 32 + hi * 16) ^ swzm);
        short8 ah = *(const short8*)(smem + 0 * PLANE + koff);
        short8 am = *(const short8*)(smem + 1 * PLANE + koff);
        acc = __builtin_amdgcn_mfma_f32_32x32x16_bf16(ah, bh, acc, 0, 0, 0);
        acc = __builtin_amdgcn_mfma_f32_32x32x16_bf16(ah, bm, acc, 0, 0, 0);
        acc = __builtin_amdgcn_mfma_f32_32x32x16_bf16(am, bh, acc, 0, 0, 0);
    }
    const short8* bp = wsL + ((size_t)(t0 + 1) * NC_TOT + ctile) * 128 + lane;
    #pragma unroll 2
    for (int t = t0 + 1; t < t0 + NKT; ++t) {
        const int koff = abase + ((t * 32 + hi * 16) ^ swzm);
        short8 ah = *(const short8*)(smem + 0 * PLANE + koff);
        short8 am = *(const short8*)(smem + 1 * PLANE + koff);
        short8 cbh = bp[0];
        short8 cbm = bp[64];
        bp += NC_TOT * 128;
        acc = __builtin_amdgcn_mfma_f32_32x32x16_bf16(ah, cbh, acc, 0, 0, 0);
        acc = __builtin_amdgcn_mfma_f32_32x32x16_bf16(ah, cbm, acc, 0, 0, 0);
        acc = __builtin_amdgcn_mfma_f32_32x32x16_bf16(am, cbh, acc, 0, 0, 0);
    }
}

// activation (in-place, pre-barrier, register-only) + pair-split + store to LDS planes.
// NOTE: no trailing barrier — caller issues next-layer B prefetch, then __syncthreads().
__device__ __forceinline__ void act_store_lds(f32x16& acc, const int* __restrict__ act,
                                              char* smem, int ctile, int lane) {
    const int hi = lane >> 5, ln31 = lane & 31;
    const int col = ctile * 32 + ln31;
    const int aid = act[col];
    const int kbyte = 2 * col;
    #pragma unroll
    for (int rr = 0; rr < 16; ++rr) acc[rr] = apply_act(aid, acc[rr]);  // overlaps other waves' reads
    __syncthreads();   // everyone done reading previous planes
    #pragma unroll
    for (int p = 0; p < 8; ++p) {
        const int rr0 = 2 * p;
        unsigned int hp, mp;
        split2_pair(acc[rr0], acc[rr0 + 1], hp, mp);
        const int row0 = (rr0 & 3) + 8 * (rr0 >> 2) + 4 * hi;   // rr0 even -> rr0+1 = row0+1
        const int a0 = row0 * 512 + (kbyte ^ ((row0 & 7) << 4));
        const int a1 = (row0 + 1) * 512 + (kbyte ^ (((row0 + 1) & 7) << 4));
        *(unsigned short*)(smem + 0 * PLANE + a0) = (unsigned short)hp;
        *(unsigned short*)(smem + 0 * PLANE + a1) = (unsigned short)(hp >> 16);
        *(unsigned short*)(smem + 1 * PLANE + a0) = (unsigned short)mp;
        *(unsigned short*)(smem + 1 * PLANE + a1) = (unsigned short)(mp >> 16);
    }
}

__global__ __launch_bounds__(512, 8)
void wann_mfma(const float* __restrict__ x,
               const float* __restrict__ W0,
               const unsigned short* __restrict__ ws,
               const int* __restrict__ a1, const int* __restrict__ a2,
               const int* __restrict__ a3,
               float* __restrict__ out) {
    extern __shared__ char smem[];           // 2 planes x 16 KiB
    const int tid = threadIdx.x;
    const int lane = tid & 63;
    const int wid = tid >> 6;                // 0..7 = ctile (L1/L2)
    const int ln31 = lane & 31;
    const int hi = lane >> 5;
    const int row0 = blockIdx.x * TB;

    const short8* wsv  = (const short8*)ws;
    const short8* wsL0 = wsv;
    const short8* wsL1 = wsv + (size_t)128 * 128;
    const short8* wsL2 = wsv + (size_t)256 * 128;

    // ---- issue layer-1 t=0 B prefetch before staging (drains under staging) ----
    const short8* p0 = wsL0 + (size_t)wid * 128 + lane;
    short8 b0h = p0[0], b0m = p0[64];

    // ---- stage x[row0:row0+32, :]: float4 -> pair-split -> b64 LDS writes ----
    {
        const float4* xv = (const float4*)(x + (size_t)row0 * 256);
        #pragma unroll
        for (int p = 0; p < 4; ++p) {
            const int f = p * 512 + tid;     // 0..2047
            const int r = f >> 6;            // row 0..31
            const int swz = (r & 7) << 4;
            const int kb0 = (f & 63) * 8;    // byte offset of the 4 bf16 slots (8B aligned)
            const float4 v = xv[f];
            unsigned int h01, m01, h23, m23;
            split2_pair(v.x, v.y, h01, m01);
            split2_pair(v.z, v.w, h23, m23);
            // swizzle only flips bits 4-6 -> 8B block stays contiguous & aligned
            const int a0 = r * 512 + (kb0 ^ swz);
            *(unsigned long long*)(smem + 0 * PLANE + a0) =
                (unsigned long long)h01 | ((unsigned long long)h23 << 32);
            *(unsigned long long*)(smem + 1 * PLANE + a0) =
                (unsigned long long)m01 | ((unsigned long long)m23 << 32);
        }
    }
    __syncthreads();

    f32x16 acc;

    // ---- layer 1 (bias = W0 row 0), ctile = wid ----
    {
        const float b = W0[wid * 32 + ln31];
        #pragma unroll
        for (int rr = 0; rr < 16; ++rr) acc[rr] = b;
        gemm_layer<8, 16>(wsL0, smem, acc, wid, lane, 0, b0h, b0m);
        act_store_lds(acc, a1, smem, wid, lane);
    }
    // layer-2 t=0 B prefetch across the barrier
    const short8* p1 = wsL1 + (size_t)wid * 128 + lane;
    short8 b1h = p1[0], b1m = p1[64];
    __syncthreads();

    // ---- layer 2 ----
    {
        #pragma unroll
        for (int rr = 0; rr < 16; ++rr) acc[rr] = 0.0f;
        gemm_layer<8, 16>(wsL1, smem, acc, wid, lane, 0, b1h, b1m);
        act_store_lds(acc, a2, smem, wid, lane);
    }
    // ---- layer 3: split-K, all 8 waves. wave = (kh, c3) ----
    const int c3 = wid & 3, kh = wid >> 2, t0 = kh * 8;
    const short8* p2 = wsL2 + ((size_t)(t0 * 4 + c3)) * 128 + lane;
    short8 b2h = p2[0], b2m = p2[64];
    __syncthreads();

    {
        #pragma unroll
        for (int rr = 0; rr < 16; ++rr) acc[rr] = 0.0f;
        gemm_layer<4, 8>(wsL2, smem, acc, c3, lane, t0, b2h, b2m);
    }
    __syncthreads();                          // all plane reads done; planes reusable
    float* red = (float*)smem;                // 16 KB scratch for k-half partials
    if (kh == 1) {
        const int base = ((wid - 4) * 64 + lane) * 16;
        #pragma unroll
        for (int q = 0; q < 4; ++q) {
            float4 v = make_float4(acc[4*q], acc[4*q+1], acc[4*q+2], acc[4*q+3]);
            *(float4*)(red + base + 4 * q) = v;
        }
    }
    __syncthreads();
    if (kh == 0) {
        const int base = (wid * 64 + lane) * 16;
        #pragma unroll
        for (int q = 0; q < 4; ++q) {
            const float4 v = *(const float4*)(red + base + 4 * q);
            acc[4*q] += v.x; acc[4*q+1] += v.y; acc[4*q+2] += v.z; acc[4*q+3] += v.w;
        }
        const int col = c3 * 32 + ln31;
        const int aid = a3[col];
        #pragma unroll
        for (int rr = 0; rr < 16; ++rr) {
            const float v = apply_act(aid, acc[rr]);
            const int orow = (rr & 3) + 8 * (rr >> 2) + 4 * hi;
            out[(size_t)(row0 + orow) * 128 + col] = v;
        }
    }
}

extern "C" void kernel_launch(void* const* d_in, const int* in_sizes, int n_in,
                              void* d_out, int out_size, void* d_ws, size_t ws_size,
                              hipStream_t stream) {
    const float* x  = (const float*)d_in[0];
    const float* W0 = (const float*)d_in[1];   // [257,256], row 0 = bias
    const float* W1 = (const float*)d_in[2];   // [256,256]
    const float* W2 = (const float*)d_in[3];   // [256,128]
    const int*   a1 = (const int*)d_in[4];
    const int*   a2 = (const int*)d_in[5];
    const int*   a3 = (const int*)d_in[6];
    float* out = (float*)d_out;

    unsigned short* ws = (unsigned short*)d_ws;   // 655360 B packed bf16 fragments

    hipFuncSetAttribute(reinterpret_cast<const void*>(wann_mfma),
                        hipFuncAttributeMaxDynamicSharedMemorySize, 2 * PLANE);

    hipLaunchKernelGGL(pack_w, dim3(80), dim3(256), 0, stream, W0, W1, W2, ws);

    const int B = in_sizes[0] / 256;           // 65536
    hipLaunchKernelGGL(wann_mfma, dim3(B / TB), dim3(512), 2 * PLANE, stream,
                       x, W0, ws, a1, a2, a3, out);
}